// Round 6
// baseline (389.651 us; speedup 1.0000x reference)
//
#include <hip/hip_runtime.h>
#include <hip/hip_bf16.h>
#include <stdint.h>

// out[2048,256] = x[2048,32768] @ W[32768,256],
// W[k,r] = U0[k&31, r] * U1[(k>>5)&31, r] * U2[k>>10, r]
//
// R6: R5 (fused W-gen, atomic-free split-K) + LDS DOUBLE BUFFER so the main
// loop needs only ONE __syncthreads per K-tile (was 2). R5 post-mortem: the
// controllable window is ~72us of kernel time after the 2x ~158us harness
// poison fills; gemm ran at only ~5.1 TB/s because the single-buffer
// 2-barrier loop drains all 8 waves 64 times. Dbuf: stage tile it+1 into
// buf^1 while computing tile it from buf -> write/read never touch the same
// buffer within an iter; buf b is read at iter it (before barrier it) and
// rewritten at iter it+1 (after barrier it) -> 1 barrier/iter is safe.
//
// Unchanged from R5 (best measured config):
//   - SK=16, BM=64 -> 512 blocks (2/CU, 16 waves/CU), 8 waves = 1x8 column
//     strips (64r x 32c, acc[4][2]).
//   - B-frag synthesis in regs: i0 = quad*8+e (fixed), i1 = (2*it+ks)&31
//     (prefetched 1 iter ahead), i2 = sk*2 + (it>>4) (preloaded).
//   - x prefetched 2 K-tiles ahead in regs (in flight across barrier).
//   - bf16 round-half-up pack; XOR-swizzled LDS ds_write_b128/ds_read_b128.
//   - plain coalesced partial-tile stores to ws[sk][row][col]; tiny
//     deterministic reduce kernel sums 16 partials.

#define K_DIM 32768
#define R_DIM 256
#define BM 64
#define BK 64
#define SK 16
#define KC (K_DIM / SK)   // 2048 K per block
#define NKI (KC / BK)     // 32 iterations
#define ABUF (BM * 64)    // uint16 elems per LDS buffer (8 KB)
#define OUT_ELEMS (2048u * 256u)   // 524288 floats, 2 MB

typedef float f32x4 __attribute__((ext_vector_type(4)));
typedef short s16x8 __attribute__((ext_vector_type(8)));

// pack two fp32 -> two bf16 (round-half-up via +0x8000, then v_perm byte pick)
__device__ __forceinline__ uint32_t pack2_bf16(float a, float b) {
    uint32_t ua = __builtin_bit_cast(uint32_t, a) + 0x8000u;
    uint32_t ub = __builtin_bit_cast(uint32_t, b) + 0x8000u;
    return __builtin_amdgcn_perm(ub, ua, 0x07060302u);
}

__global__ __launch_bounds__(512, 4) void gemm_fused_kernel(
        const float* __restrict__ x, const float* __restrict__ U0,
        const float* __restrict__ U1, const float* __restrict__ U2,
        float* __restrict__ ws) {
    __shared__ uint16_t As[2 * ABUF];   // 16 KB bf16, double-buffered

    const uint32_t bid  = blockIdx.x;
    const uint32_t sk   = bid & 15u;   // K split
    const uint32_t mblk = bid >> 4;    // x row block, 0..31

    const uint32_t tid  = threadIdx.x;
    const uint32_t lane = tid & 63u;
    const uint32_t wave = tid >> 6;    // 0..7: 32-column strip
    const uint32_t mloc = lane & 15u;
    const uint32_t quad = lane >> 4;

    // ---- B-fragment generation state (registers, loaded once) ----
    uint32_t rg[2];
    rg[0] = wave * 32u + mloc;
    rg[1] = rg[0] + 16u;
    float u0[2][8];   // U0[quad*8+e][rg[nt]] -- i0 iteration-invariant
#pragma unroll
    for (int nt = 0; nt < 2; ++nt)
#pragma unroll
        for (int e = 0; e < 8; ++e)
            u0[nt][e] = U0[(quad * 8u + (uint32_t)e) * 256u + rg[nt]];
    float u2v[2][2];  // U2[sk*2 + half][rg[nt]]
#pragma unroll
    for (int h = 0; h < 2; ++h)
#pragma unroll
        for (int nt = 0; nt < 2; ++nt)
            u2v[h][nt] = U2[(sk * 2u + (uint32_t)h) * 256u + rg[nt]];

    // ---- A staging: thread owns row arow, k-chunk ac (8 fp32 = 32B) ----
    const uint32_t ac   = tid & 7u;
    const uint32_t arow = tid >> 3;                  // 0..63
    const uint32_t aoff = (ac ^ (arow & 7u)) * 8u;   // XOR swizzle (u16 units)
    const uint32_t astg = arow * 64u + aoff;         // staging slot in a buffer
    const float* xg = x + (size_t)(mblk * BM + arow) * K_DIM + sk * KC + ac * 8u;

    const uint32_t aBase = mloc * 64u;               // + mt*1024 + sw

    // prologue: x tiles 0,1 into regs; U1 for it=0; stage tile 0 into buf 0
    f32x4 c0 = *(const f32x4*)(xg);
    f32x4 c1 = *(const f32x4*)(xg + 4);
    f32x4 n0 = *(const f32x4*)(xg + BK);
    f32x4 n1 = *(const f32x4*)(xg + BK + 4);
    f32x4 m0, m1;
    float u1c00 = U1[0u * 256u + rg[0]];   // i1(it=0,ks=0)=0
    float u1c01 = U1[0u * 256u + rg[1]];
    float u1c10 = U1[1u * 256u + rg[0]];   // i1(it=0,ks=1)=1
    float u1c11 = U1[1u * 256u + rg[1]];
    float u1n00, u1n01, u1n10, u1n11;

    *(uint4*)(&As[astg]) = make_uint4(
        pack2_bf16(c0[0], c0[1]), pack2_bf16(c0[2], c0[3]),
        pack2_bf16(c1[0], c1[1]), pack2_bf16(c1[2], c1[3]));
    __syncthreads();

    f32x4 acc[4][2];
#pragma unroll
    for (int i = 0; i < 4; ++i)
#pragma unroll
        for (int j = 0; j < 2; ++j) acc[i][j] = (f32x4){0.f, 0.f, 0.f, 0.f};

#pragma unroll
    for (int half = 0; half < 2; ++half) {
        const float u2c0 = u2v[half][0];
        const float u2c1 = u2v[half][1];

#pragma unroll
        for (int itl = 0; itl < 16; ++itl) {
            const uint32_t it = (uint32_t)half * 16u + (uint32_t)itl;
            const uint32_t cur = it & 1u;

            // issue global prefetch of x tile it+2 (in flight across barrier)
            if (it + 2u < NKI) {
                const float* g = xg + (it + 2u) * BK;
                m0 = *(const f32x4*)(g);
                m1 = *(const f32x4*)(g + 4);
            }
            // prefetch U1 scalars for it+1 (mask wraps harmlessly at it=31)
            {
                const uint32_t i1a = (2u * (it + 1u)) & 31u;
                const uint32_t i1b = (2u * (it + 1u) + 1u) & 31u;
                u1n00 = U1[i1a * 256u + rg[0]];
                u1n01 = U1[i1a * 256u + rg[1]];
                u1n10 = U1[i1b * 256u + rg[0]];
                u1n11 = U1[i1b * 256u + rg[1]];
            }

            // stage tile it+1 into the OTHER buffer (no barrier needed first:
            // all waves' reads of that buffer finished before barrier it-1)
            if (it + 1u < NKI) {
                *(uint4*)(&As[(cur ^ 1u) * ABUF + astg]) = make_uint4(
                    pack2_bf16(n0[0], n0[1]), pack2_bf16(n0[2], n0[3]),
                    pack2_bf16(n1[0], n1[1]), pack2_bf16(n1[2], n1[3]));
            }

            // compute tile it from buf[cur]
#pragma unroll
            for (int ks = 0; ks < 2; ++ks) {
                const uint32_t sw = (((uint32_t)ks * 4u + quad) ^ (mloc & 7u)) * 8u;
                s16x8 af[4];
#pragma unroll
                for (int mt = 0; mt < 4; ++mt)
                    af[mt] = *(const s16x8*)(
                        &As[cur * ABUF + aBase + (uint32_t)mt * 1024u + sw]);
#pragma unroll
                for (int nt = 0; nt < 2; ++nt) {
                    const float u1s = ks ? (nt ? u1c11 : u1c10)
                                         : (nt ? u1c01 : u1c00);
                    const float m = u1s * (nt ? u2c1 : u2c0);
                    union { uint32_t u[4]; s16x8 v; } bb;
                    bb.u[0] = pack2_bf16(u0[nt][0] * m, u0[nt][1] * m);
                    bb.u[1] = pack2_bf16(u0[nt][2] * m, u0[nt][3] * m);
                    bb.u[2] = pack2_bf16(u0[nt][4] * m, u0[nt][5] * m);
                    bb.u[3] = pack2_bf16(u0[nt][6] * m, u0[nt][7] * m);
#pragma unroll
                    for (int mt = 0; mt < 4; ++mt)
                        acc[mt][nt] = __builtin_amdgcn_mfma_f32_16x16x32_bf16(
                            af[mt], bb.v, acc[mt][nt], 0, 0, 0);
                }
            }
            // single barrier per iteration: covers (a) stage writes of it+1
            // before their reads at it+1, (b) reads of buf[cur] before its
            // rewrite at it+1.
            __syncthreads();

            // shift pipelines
            n0 = m0; n1 = m1;
            u1c00 = u1n00; u1c01 = u1n01; u1c10 = u1n10; u1c11 = u1n11;
        }
    }

    // epilogue: plain coalesced stores of the partial tile (NO atomics).
    // ws layout: [sk][global_row][col] fp32 -> sk*524288 + row*256 + col
    const uint32_t orow0 = mblk * BM + quad * 4u;
    const uint32_t ocol0 = wave * 32u + mloc;
    float* wsk = ws + (size_t)sk * OUT_ELEMS;
#pragma unroll
    for (int mt = 0; mt < 4; ++mt) {
#pragma unroll
        for (int nt = 0; nt < 2; ++nt) {
            float* po = wsk + (size_t)(orow0 + (uint32_t)mt * 16u) * R_DIM +
                        ocol0 + (uint32_t)nt * 16u;
#pragma unroll
            for (int i = 0; i < 4; ++i)
                po[(size_t)i * R_DIM] = acc[mt][nt][i];
        }
    }
}

// sum the 16 split-K partials; deterministic order, fully coalesced.
__global__ __launch_bounds__(256) void reduce_kernel(
        const float* __restrict__ ws, float* __restrict__ out) {
    const uint32_t f = (blockIdx.x * 256u + threadIdx.x) * 4u;  // grid covers 2MB
    f32x4 s = *(const f32x4*)(ws + f);
#pragma unroll
    for (int sk = 1; sk < SK; ++sk)
        s += *(const f32x4*)(ws + (size_t)sk * OUT_ELEMS + f);
    *(f32x4*)(out + f) = s;
}

extern "C" void kernel_launch(void* const* d_in, const int* in_sizes, int n_in,
                              void* d_out, int out_size, void* d_ws, size_t ws_size,
                              hipStream_t stream) {
    const float* x  = (const float*)d_in[0];
    const float* U0 = (const float*)d_in[1];
    const float* U1 = (const float*)d_in[2];
    const float* U2 = (const float*)d_in[3];
    float* out = (float*)d_out;
    float* ws  = (float*)d_ws;   // needs SK * 2 MB = 32 MB

    // fused W-gen + split-K MFMA GEMM -> fp32 partials in ws (no atomics)
    gemm_fused_kernel<<<512, 512, 0, stream>>>(x, U0, U1, U2, ws);
    // deterministic split-K reduction: 524288 floats / (256 thr * 4) = 512 blocks
    reduce_kernel<<<512, 256, 0, stream>>>(ws, out);
}